// Round 8
// baseline (93.841 us; speedup 1.0000x reference)
//
#include <hip/hip_runtime.h>
#include <stdint.h>

typedef float  v4f  __attribute__((ext_vector_type(4)));
typedef __bf16 v8bf __attribute__((ext_vector_type(8)));
typedef __bf16 v4bf __attribute__((ext_vector_type(4)));
typedef unsigned short u16;

#define NEGBIG (-1.0e9f)

static __device__ __forceinline__ uint2 pack4(v4f a){
  v4bf r;
  r[0]=(__bf16)a[0]; r[1]=(__bf16)a[1]; r[2]=(__bf16)a[2]; r[3]=(__bf16)a[3];
  return __builtin_bit_cast(uint2, r);
}
static __device__ __forceinline__ v8bf pack8(float4 a, float4 b){
  v8bf r;
  r[0]=(__bf16)a.x; r[1]=(__bf16)a.y; r[2]=(__bf16)a.z; r[3]=(__bf16)a.w;
  r[4]=(__bf16)b.x; r[5]=(__bf16)b.y; r[6]=(__bf16)b.z; r[7]=(__bf16)b.w;
  return r;
}
static __device__ __forceinline__ v4f mfma16(v8bf a, v8bf b, v4f c){
  return __builtin_amdgcn_mfma_f32_16x16x32_bf16(a, b, c, 0, 0, 0);
}

// Butterfly: convert MFMA D-layout columns (lane: n=l15 fixed, m rows spread as
// tile*16+g*4+r) into an A/B fragment (lane: n=l15, k = g*8+j, j=0..7).
static __device__ __forceinline__ v8bf bfly(uint2 t0, uint2 t1, int srcA, int srcB, int hi){
  int a0 = __shfl((int)t0.x, srcA), a1 = __shfl((int)t0.y, srcA);
  int b0 = __shfl((int)t1.x, srcA), b1 = __shfl((int)t1.y, srcA);
  int a2 = __shfl((int)t0.x, srcB), a3 = __shfl((int)t0.y, srcB);
  int b2 = __shfl((int)t1.x, srcB), b3 = __shfl((int)t1.y, srcB);
  uint4 r;
  r.x = hi ? (unsigned)b0 : (unsigned)a0;
  r.y = hi ? (unsigned)b1 : (unsigned)a1;
  r.z = hi ? (unsigned)b2 : (unsigned)a2;
  r.w = hi ? (unsigned)b3 : (unsigned)a3;
  return __builtin_bit_cast(v8bf, r);
}

// ---------------------------------------------------------------------------
// Kernel 0: convert the four weight matrices to bf16 (each 32768 elements).
// ---------------------------------------------------------------------------
__global__ __launch_bounds__(256) void k_pre(
    const float* __restrict__ WQ, const float* __restrict__ WK,
    const float* __restrict__ WV, const float* __restrict__ Ww,
    u16* __restrict__ wq, u16* __restrict__ wk,
    u16* __restrict__ wv, u16* __restrict__ ww)
{
  const int seg = blockIdx.x >> 5;
  const int idx = ((blockIdx.x & 31)*256 + threadIdx.x)*4;
  const float* s = (seg==0) ? WQ : (seg==1) ? WK : (seg==2) ? WV : Ww;
  u16*       dst = (seg==0) ? wq : (seg==1) ? wk : (seg==2) ? wv : ww;
  float4 v = *(const float4*)(s + idx);
  v4f a; a[0]=v.x; a[1]=v.y; a[2]=v.z; a[3]=v.w;
  *(uint2*)(dst + idx) = pack4(a);
}

// ---------------------------------------------------------------------------
// LDS map (bytes).  Total 53248 -> 3 blocks/CU possible (3x53248 = 159744
// <= 163840).  This round tests the one unexplored occupancy cell:
// grid > 2/CU  x  small LDS  x  STAGED hot weights (wq,wk)  x  64 VGPR.
// (Round 3's grid-1024 failure had ALL weights global -- confounded.)
//  rk   [128 key][64 d] bf16, 128B rows, XOR swz        [0, 16K)
//  vt   [64 d][128 key] bf16, 256B rows, XOR swz        [16K, 32K)
//  WS   wq|wk head slice (16K, single-buffered)         [32K, 48K)
//  POOL 2 x 2KB (8 waves x 64 f32), double-buffered     [48K, 52K)
// wv: global (round-2 verified path); ww,bias: global (round-0 verified
// paths; staging them measured ~neutral in round 5).
// HARD CONSTRAINT: VGPR <= 64 (round 6: 88 VGPR -> 1 block/CU, -27us).
// ---------------------------------------------------------------------------
#define LDS_RK    0
#define LDS_VT    16384
#define LDS_WS    32768
#define LDS_POOL  49152
#define LDS_TOTAL 53248

// ---------------------------------------------------------------------------
// Kernel 1 (mega-fused): block = (hgi, tile); 2 heads; 8 waves; wave w owns
// q rows [16w,16w+16).  bid = hgi*256 + tile so all 4 head-groups of a tile
// share an XCD (256 % 8 == 0) -> Q/K/V and weights L2-hot.
// ---------------------------------------------------------------------------
__global__ __launch_bounds__(512, 4) void k_fused(
    const float* __restrict__ Q, const float* __restrict__ K, const float* __restrict__ V,
    const u16* __restrict__ wqbf, const u16* __restrict__ wkbf,
    const u16* __restrict__ wvbf, const u16* __restrict__ wwbf,
    const float* __restrict__ bQ, const float* __restrict__ bK, const float* __restrict__ bV,
    float* __restrict__ oVW, float* __restrict__ pool)
{
  extern __shared__ char lds[];

  const int bid = blockIdx.x;
  const int tile = bid & 255;          // b*64 + nb
  const int hgi  = bid >> 8;           // head-group 0..3 (2 heads each)
  const int b = tile >> 6, nb = tile & 63;
  const int rowbase = tile * 128;
  const int tid = threadIdx.x;
  const int w = tid >> 6, l = tid & 63;
  const int l15 = l & 15, g = l >> 4;
  const int swz = (l15 & 7) << 4;
  const int srcA = ((l >> 4) & 1) * 32 + l15;
  const int srcB = srcA + 16;
  const int hi_  = l >> 5;             // g>>1
  const float scale = 0.125f;

  // ---- async weight stage: 16KB (wq|wk slice of head hn) ----
  auto STAGE = [&](int hn){
    #pragma unroll
    for (int i = 0; i < 2; ++i){
      const int obase = w*2048 + i*1024;           // wave-uniform, [0,16K)
      const int m   = obase >> 13;                 // 0:wq 1:wk
      const int row = ((obase & 8191) >> 7) + (l >> 3);
      const int sc  = (l & 7) << 4;
      const u16* basep = (m == 0) ? wqbf : wkbf;
      const char* src = (const char*)basep + hn*8192 + row*128 + (sc ^ ((row & 7) << 4));
      __builtin_amdgcn_global_load_lds(
          (const __attribute__((address_space(1))) unsigned int*)src,
          (__attribute__((address_space(3))) unsigned int*)(lds + LDS_WS + obase),
          16, 0, 0);
    }
  };

  STAGE(hgi*2);

  // ---- persistent X fragments (this wave's 16 rows), f32 -> bf16 ----
  const int xrow = rowbase + w*16 + l15;
  v8bf xq[2], xk[2], xv[2];
  #pragma unroll
  for (int ks = 0; ks < 2; ++ks){
    const float* qp = Q + xrow*64 + ks*32 + g*8;
    const float* kp = K + xrow*64 + ks*32 + g*8;
    const float* vp = V + xrow*64 + ks*32 + g*8;
    xq[ks] = pack8(*(const float4*)qp, *(const float4*)(qp+4));
    xk[ks] = pack8(*(const float4*)kp, *(const float4*)(kp+4));
    xv[ks] = pack8(*(const float4*)vp, *(const float4*)(vp+4));
  }

  __syncthreads();                 // B0: drains stage(h0) + X

  v4f acc_out[4];
  #pragma unroll
  for (int mt = 0; mt < 4; ++mt){ v4f z = {0.f,0.f,0.f,0.f}; acc_out[mt] = z; }

  const int q = w*16 + l15;
  const int wfo = l15*64 + g*8;    // per-lane offset in a [*][64] u16 panel

  for (int hi = 0; hi < 2; ++hi){
    const int h  = hgi*2 + hi;
    const int hb = h*64;
    char* wsb = lds + LDS_WS;
    const u16* wvp = wvbf + hb*64 + wfo;

    // ======== proj Q,K (A=W from LDS, B=X regs -> D[m=d][n=q]) ========
    v4f aq[4], ak[4];
    #pragma unroll
    for (int mt = 0; mt < 4; ++mt){
      float4 b4 = *(const float4*)(bQ + hb + mt*16 + g*4);
      aq[mt][0]=b4.x; aq[mt][1]=b4.y; aq[mt][2]=b4.z; aq[mt][3]=b4.w;
      float4 c4 = *(const float4*)(bK + hb + mt*16 + g*4);
      ak[mt][0]=c4.x; ak[mt][1]=c4.y; ak[mt][2]=c4.z; ak[mt][3]=c4.w;
    }
    #pragma unroll
    for (int ks = 0; ks < 2; ++ks){
      #pragma unroll
      for (int mt = 0; mt < 4; ++mt){
        v8bf wqf = *(const v8bf*)(wsb + (mt*16 + l15)*128 + ((ks*64 + g*16) ^ swz));
        aq[mt] = mfma16(wqf, xq[ks], aq[mt]);
      }
      #pragma unroll
      for (int mt = 0; mt < 4; ++mt){
        v8bf wkf = *(const v8bf*)(wsb + 8192 + (mt*16 + l15)*128 + ((ks*64 + g*16) ^ swz));
        ak[mt] = mfma16(wkf, xk[ks], ak[mt]);
      }
    }
    // qf fragments via butterfly (registers only)
    uint2 pq[4];
    #pragma unroll
    for (int mt = 0; mt < 4; ++mt) pq[mt] = pack4(aq[mt]);
    v8bf qf0 = bfly(pq[0], pq[1], srcA, srcB, hi_);
    v8bf qf1 = bfly(pq[2], pq[3], srcA, srcB, hi_);
    // rk write (cross-wave)
    #pragma unroll
    for (int mt = 0; mt < 4; ++mt)
      *(uint2*)(lds + LDS_RK + (w*16 + l15)*128 + ((mt*32 + g*8) ^ swz)) = pack4(ak[mt]);

    // ======== proj V (A=X regs, B=W global -> D[m=key][n=d]) -> vt[d][key] ====
    {
      v4f av[4];
      #pragma unroll
      for (int nt = 0; nt < 4; ++nt){
        float bs = bV[hb + nt*16 + l15];
        av[nt][0]=bs; av[nt][1]=bs; av[nt][2]=bs; av[nt][3]=bs;
      }
      #pragma unroll
      for (int ks = 0; ks < 2; ++ks)
        #pragma unroll
        for (int nt = 0; nt < 4; ++nt){
          v8bf wvf = *(const v8bf*)(wvp + nt*1024 + ks*32);
          av[nt] = mfma16(xv[ks], wvf, av[nt]);
        }
      #pragma unroll
      for (int nt = 0; nt < 4; ++nt)
        *(uint2*)(lds + LDS_VT + (nt*16 + l15)*256 + ((w*32 + g*8) ^ swz)) = pack4(av[nt]);
    }

    __syncthreads();   // B1: rk, vt visible; wq/wk reads done

    // ---- stage next head's weights ----
    if (hi < 1) STAGE(h+1);

    // ---- pool store for previous head (reads pool buffer (hi-1)&1) ----
    if (hi > 0 && tid < 64){
      const float* pr = (const float*)(lds + LDS_POOL + ((hi-1)&1)*2048);
      float s_ = 0.f;
      #pragma unroll
      for (int p = 0; p < 8; ++p) s_ += pr[p*64 + tid];
      pool[(b*8 + h-1)*4096 + nb*64 + tid] = s_ * (1.0f/128.0f);
    }

    // ======== S^T = K.Q^T + no-max softmax (causal skip: mt<=w) ========
    float sum = 0.f;
    uint2 pp[8];
    __builtin_amdgcn_s_setprio(1);
    #pragma unroll
    for (int mt = 0; mt < 8; ++mt){
      if (mt > w){ uint2 z; z.x = 0u; z.y = 0u; pp[mt] = z; continue; }
      v4f s4 = {0.f,0.f,0.f,0.f};
      s4 = mfma16(*(const v8bf*)(lds + LDS_RK + (mt*16 + l15)*128 + ((0*64 + g*16) ^ swz)), qf0, s4);
      s4 = mfma16(*(const v8bf*)(lds + LDS_RK + (mt*16 + l15)*128 + ((1*64 + g*16) ^ swz)), qf1, s4);
      v4f e4;
      #pragma unroll
      for (int r = 0; r < 4; ++r){
        const int key = mt*16 + g*4 + r;
        float v_ = (key <= q) ? s4[r]*scale : NEGBIG;
        float p = __expf(v_);
        e4[r] = p;
        sum += p;
      }
      pp[mt] = pack4(e4);
    }
    __builtin_amdgcn_s_setprio(0);
    sum += __shfl_xor(sum, 16);
    sum += __shfl_xor(sum, 32);
    const float inv = 1.0f / sum;

    // ======== O = V^T.P (A=vt, B=P-frags -> D[m=d][n=q]) ========
    v4f oa[4];
    #pragma unroll
    for (int mt = 0; mt < 4; ++mt){ v4f z = {0.f,0.f,0.f,0.f}; oa[mt] = z; }
    const int WKn = (w >> 1) + 1;
    __builtin_amdgcn_s_setprio(1);
    #pragma unroll
    for (int ks = 0; ks < 4; ++ks){
      if (ks >= WKn) continue;
      v8bf pf = bfly(pp[2*ks], pp[2*ks+1], srcA, srcB, hi_);
      #pragma unroll
      for (int mt = 0; mt < 4; ++mt){
        v8bf vf = *(const v8bf*)(lds + LDS_VT + (mt*16 + l15)*256 + ((ks*64 + g*16) ^ swz));
        oa[mt] = mfma16(vf, pf, oa[mt]);
      }
    }
    __builtin_amdgcn_s_setprio(0);

    // deferred softmax normalization
    #pragma unroll
    for (int mt = 0; mt < 4; ++mt){
      oa[mt][0]*=inv; oa[mt][1]*=inv; oa[mt][2]*=inv; oa[mt][3]*=inv;
    }

    // ---- pool partial: reduce over q (= over l15 lanes) ----
    {
      float* prd = (float*)(lds + LDS_POOL + (hi&1)*2048);
      #pragma unroll
      for (int mt = 0; mt < 4; ++mt){
        v4f v = oa[mt];
        #pragma unroll
        for (int s_ = 1; s_ < 16; s_ <<= 1){
          v[0] += __shfl_xor(v[0], s_);
          v[1] += __shfl_xor(v[1], s_);
          v[2] += __shfl_xor(v[2], s_);
          v[3] += __shfl_xor(v[3], s_);
        }
        if (l15 == 0)
          *(float4*)(prd + w*64 + mt*16 + g*4) = make_float4(v[0], v[1], v[2], v[3]);
      }
    }

    // ======== out-proj accumulate: acc_out += Ww_h . O^T (W global) ========
    uint2 po[4];
    #pragma unroll
    for (int mt = 0; mt < 4; ++mt) po[mt] = pack4(oa[mt]);
    v8bf of0 = bfly(po[0], po[1], srcA, srcB, hi_);
    v8bf of1 = bfly(po[2], po[3], srcA, srcB, hi_);
    #pragma unroll
    for (int ks = 0; ks < 2; ++ks){
      v8bf off = ks ? of1 : of0;
      #pragma unroll
      for (int mt = 0; mt < 4; ++mt){
        v8bf wf = *(const v8bf*)(wwbf + (mt*16 + l15)*512 + hb + ks*32 + g*8);
        acc_out[mt] = mfma16(wf, off, acc_out[mt]);
      }
    }

    __syncthreads();   // B2: drains stage(h+1); protects rk/vt/WS reuse
  }

  // ---- pool store for last head of this group (buffer (2-1)&1 = 1) ----
  if (tid < 64){
    const float* pr = (const float*)(lds + LDS_POOL + 2048);
    float s_ = 0.f;
    #pragma unroll
    for (int p = 0; p < 8; ++p) s_ += pr[p*64 + tid];
    pool[(b*8 + hgi*2 + 1)*4096 + nb*64 + tid] = s_ * (1.0f/128.0f);
  }

  // ---- store out-proj partial: oVW[hgi][row][dout] ----
  #pragma unroll
  for (int mt = 0; mt < 4; ++mt){
    float4 o;
    o.x = acc_out[mt][0]; o.y = acc_out[mt][1];
    o.z = acc_out[mt][2]; o.w = acc_out[mt][3];
    *(float4*)(oVW + hgi*2097152 + (rowbase + w*16 + l15)*64 + mt*16 + g*4) = o;
  }
}

// ---------------------------------------------------------------------------
// Kernel 2 (merged global-attn + final), WAVE-PER-HEAD: wave w of block
// (b,nb) computes row nb of head w's pooled global attention straight from
// `pool` (L2-resident), then its out-proj contribution.  2 barriers.
// out = sum_{g=0..3} oVW[g] + gadd.
// ---------------------------------------------------------------------------
__global__ __launch_bounds__(512) void k_final(
    const float* __restrict__ oVW, const float* __restrict__ Ww, const float* __restrict__ Wb,
    const float* __restrict__ pool, float* __restrict__ out)
{
  __shared__ float prow[8][64];
  __shared__ float grow[8][64];
  __shared__ float gred[8][64];
  __shared__ float gadd[64];

  const int bid = blockIdx.x;     // b*64 + nb
  const int b = bid >> 6, nb = bid & 63;
  const int rowbase = bid * 128;
  const int tid = threadIdx.x;
  const int w = tid >> 6, l = tid & 63;

  const float* pb = pool + (b*8 + w)*4096;   // this wave's head tile [64k][64d]

  // ---- S row: lane l = key k ----
  float dot = 0.f;
  #pragma unroll
  for (int dd = 0; dd < 16; ++dd){
    float4 t  = *(const float4*)(pb + l*64  + dd*4);
    float4 qv = *(const float4*)(pb + nb*64 + dd*4);
    dot += t.x*qv.x + t.y*qv.y + t.z*qv.z + t.w*qv.w;
  }
  float sv = (l <= nb) ? dot*0.125f : NEGBIG;
  float mx = sv;
  #pragma unroll
  for (int s = 1; s < 64; s <<= 1) mx = fmaxf(mx, __shfl_xor(mx, s));
  float p = __expf(sv - mx);
  float sum = p;
  #pragma unroll
  for (int s = 1; s < 64; s <<= 1) sum += __shfl_xor(sum, s);
  prow[w][l] = p / sum;            // wave-private write->read: no barrier

  // ---- grow[d] = sum_k prow[k]*pool[k][d] (lane l = d; coalesced) ----
  {
    float a = 0.f;
    for (int k = 0; k <= nb; ++k)          // prow[k]=0 for k>nb
      a += prow[w][k] * pb[k*64 + l];
    grow[w][l] = a;
  }

  // ---- per-head out-proj contribution: lane l = dout ----
  {
    const float* wr = Ww + l*512 + w*64;
    float c = 0.f;
    #pragma unroll
    for (int dd = 0; dd < 16; ++dd){
      float4 g4 = *(const float4*)(&grow[w][dd*4]);
      float4 w4 = *(const float4*)(wr + dd*4);
      c += g4.x*w4.x + g4.y*w4.y + g4.z*w4.z + g4.w*w4.w;
    }
    gred[w][l] = c;
  }
  __syncthreads();
  if (tid < 64){
    float s = Wb[tid];
    #pragma unroll
    for (int ph = 0; ph < 8; ++ph) s += gred[ph][tid];
    gadd[tid] = s;
  }
  __syncthreads();

  // ---- out = sum_g oVW[g] + gadd ----
  const int c4 = (tid & 15) * 4;
  float4 ga = *(const float4*)(&gadd[c4]);
  #pragma unroll
  for (int it = 0; it < 4; ++it){
    const int row = it*32 + (tid >> 4);
    const int idx = (rowbase + row)*64 + c4;
    float4 o = ga;
    #pragma unroll
    for (int s = 0; s < 4; ++s){
      float4 v = *(const float4*)(oVW + s*2097152 + idx);
      o.x += v.x; o.y += v.y; o.z += v.z; o.w += v.w;
    }
    *(float4*)(out + idx) = o;
  }
}

// ---------------------------------------------------------------------------

extern "C" void kernel_launch(void* const* d_in, const int* in_sizes, int n_in,
                              void* d_out, int out_size, void* d_ws, size_t ws_size,
                              hipStream_t stream) {
  const float* Q   = (const float*)d_in[0];
  const float* K   = (const float*)d_in[1];
  const float* V   = (const float*)d_in[2];
  const float* WQw = (const float*)d_in[3];
  const float* WQb = (const float*)d_in[4];
  const float* WKw = (const float*)d_in[5];
  const float* WKb = (const float*)d_in[6];
  const float* WVw = (const float*)d_in[7];
  const float* WVb = (const float*)d_in[8];
  const float* Ww  = (const float*)d_in[9];
  const float* Wb  = (const float*)d_in[10];

  char* ws = (char*)d_ws;
  float* oVW  = (float*)(ws + 0);          // 4 x 8,388,608 B
  float* pool = (float*)(ws + 33554432);   //   524,288 B
  u16*   wqbf = (u16*)(ws + 34078720);     //    65,536 B each
  u16*   wkbf = (u16*)(ws + 34144256);
  u16*   wvbf = (u16*)(ws + 34209792);
  u16*   wwbf = (u16*)(ws + 34275328);

  float* outp = (float*)d_out;

  k_pre<<<128, 256, 0, stream>>>(WQw, WKw, WVw, Ww, wqbf, wkbf, wvbf, wwbf);
  k_fused<<<1024, 512, LDS_TOTAL, stream>>>(Q, K, V, wqbf, wkbf, wvbf, wwbf,
                                            WQb, WKb, WVb, oVW, pool);
  k_final<<<256, 512, 0, stream>>>(oVW, Ww, Wb, pool, outp);
}

// Round 10
// 79.659 us; speedup vs baseline: 1.1780x; 1.1780x over previous
//
#include <hip/hip_runtime.h>
#include <stdint.h>

typedef float  v4f  __attribute__((ext_vector_type(4)));
typedef __bf16 v8bf __attribute__((ext_vector_type(8)));
typedef __bf16 v4bf __attribute__((ext_vector_type(4)));
typedef unsigned short u16;

#define NEGBIG (-1.0e9f)

static __device__ __forceinline__ uint2 pack4(v4f a){
  v4bf r;
  r[0]=(__bf16)a[0]; r[1]=(__bf16)a[1]; r[2]=(__bf16)a[2]; r[3]=(__bf16)a[3];
  return __builtin_bit_cast(uint2, r);
}
static __device__ __forceinline__ v8bf pack8(float4 a, float4 b){
  v8bf r;
  r[0]=(__bf16)a.x; r[1]=(__bf16)a.y; r[2]=(__bf16)a.z; r[3]=(__bf16)a.w;
  r[4]=(__bf16)b.x; r[5]=(__bf16)b.y; r[6]=(__bf16)b.z; r[7]=(__bf16)b.w;
  return r;
}
static __device__ __forceinline__ v4f mfma16(v8bf a, v8bf b, v4f c){
  return __builtin_amdgcn_mfma_f32_16x16x32_bf16(a, b, c, 0, 0, 0);
}

// s_setprio takes an IMMEDIATE (simm16) -> builtin needs a constant; grade
// per-wave priority via a wave-uniform branch over constant calls.
static __device__ __forceinline__ void setprio_graded(int w){
  if (w >= 6)      __builtin_amdgcn_s_setprio(3);
  else if (w >= 4) __builtin_amdgcn_s_setprio(2);
  else if (w >= 2) __builtin_amdgcn_s_setprio(1);
  else             __builtin_amdgcn_s_setprio(0);
}

// Butterfly: convert MFMA D-layout columns (lane: n=l15 fixed, m rows spread as
// tile*16+g*4+r) into an A/B fragment (lane: n=l15, k = g*8+j, j=0..7).
static __device__ __forceinline__ v8bf bfly(uint2 t0, uint2 t1, int srcA, int srcB, int hi){
  int a0 = __shfl((int)t0.x, srcA), a1 = __shfl((int)t0.y, srcA);
  int b0 = __shfl((int)t1.x, srcA), b1 = __shfl((int)t1.y, srcA);
  int a2 = __shfl((int)t0.x, srcB), a3 = __shfl((int)t0.y, srcB);
  int b2 = __shfl((int)t1.x, srcB), b3 = __shfl((int)t1.y, srcB);
  uint4 r;
  r.x = hi ? (unsigned)b0 : (unsigned)a0;
  r.y = hi ? (unsigned)b1 : (unsigned)a1;
  r.z = hi ? (unsigned)b2 : (unsigned)a2;
  r.w = hi ? (unsigned)b3 : (unsigned)a3;
  return __builtin_bit_cast(v8bf, r);
}

// ---------------------------------------------------------------------------
// Kernel 0: convert the four weight matrices to bf16 (each 32768 elements).
// ---------------------------------------------------------------------------
__global__ __launch_bounds__(256) void k_pre(
    const float* __restrict__ WQ, const float* __restrict__ WK,
    const float* __restrict__ WV, const float* __restrict__ Ww,
    u16* __restrict__ wq, u16* __restrict__ wk,
    u16* __restrict__ wv, u16* __restrict__ ww)
{
  const int seg = blockIdx.x >> 5;
  const int idx = ((blockIdx.x & 31)*256 + threadIdx.x)*4;
  const float* s = (seg==0) ? WQ : (seg==1) ? WK : (seg==2) ? WV : Ww;
  u16*       dst = (seg==0) ? wq : (seg==1) ? wk : (seg==2) ? wv : ww;
  float4 v = *(const float4*)(s + idx);
  v4f a; a[0]=v.x; a[1]=v.y; a[2]=v.z; a[3]=v.w;
  *(uint2*)(dst + idx) = pack4(a);
}

// ---------------------------------------------------------------------------
// LDS map (bytes).  Total 80896 -> 2 blocks/CU.  (Round-8 closed the
// occupancy question: even at 53KB LDS + grid 1024 + 64 VGPR, residency
// stays ~16 waves/CU.  Occupancy-directed moves are dead; LDS to 80KB free.)
//  rk   [128 key][64 d] bf16, 128B rows, XOR swz        [0, 16K)
//  vt   [64 d][128 key] bf16, 256B rows, XOR swz        [16K, 32K)
//  WS   wq|wk|wv head slice (24K, single-buffered)      [32K, 56K)
//  WW   Ww head column-slice, DOUBLE-buffered 2x8K      [56K, 72K)
//  POOL 2 x 2KB (8 waves x 64 f32), double-buffered     [72K, 76K)
//  BIAS bQ|bK|bV for the 4 heads of this group, 3KB     [76K, 79K)
// HARD CONSTRAINT: VGPR <= 64 (round 6: 88 VGPR -> 1 block/CU, -27us).
// ---------------------------------------------------------------------------
#define LDS_RK    0
#define LDS_VT    16384
#define LDS_WS    32768
#define LDS_WW    57344
#define LDS_POOL  73728
#define LDS_BIAS  77824
#define LDS_TOTAL 80896

// ---------------------------------------------------------------------------
// Kernel 1 (mega-fused): block = (b, nb, hg); 4 heads; 8 waves; wave w owns
// q rows [16w,16w+16).  hg = bid>>8 so a tile's two blocks (bid = t, t+256)
// share an XCD (256 % 8 == 0) -> Q/K/V L2-shared.  Wave-graded s_setprio in
// the attention span (B1->B2) attacks the triangular-work barrier convoy
// (wave w does w+1 S-tiles; B2 waits on wave 7; avg/max = 9/16).
// ---------------------------------------------------------------------------
__global__ __launch_bounds__(512, 4) void k_fused(
    const float* __restrict__ Q, const float* __restrict__ K, const float* __restrict__ V,
    const u16* __restrict__ wqbf, const u16* __restrict__ wkbf,
    const u16* __restrict__ wvbf, const u16* __restrict__ wwbf,
    const float* __restrict__ bQ, const float* __restrict__ bK, const float* __restrict__ bV,
    float* __restrict__ oVW, float* __restrict__ pool)
{
  extern __shared__ char lds[];

  const int bid = blockIdx.x;
  const int hg  = bid >> 8;            // 0 for bids 0..255, 1 for 256..511
  const int tile = bid & 255;          // b*64 + nb ; same tile -> same XCD
  const int b = tile >> 6, nb = tile & 63;
  const int rowbase = tile * 128;
  const int tid = threadIdx.x;
  const int w = tid >> 6, l = tid & 63;
  const int l15 = l & 15, g = l >> 4;
  const int swz = (l15 & 7) << 4;
  const int srcA = ((l >> 4) & 1) * 32 + l15;
  const int srcB = srcA + 16;
  const int hi_  = l >> 5;             // g>>1
  const float scale = 0.125f;

  // ---- async weight stage: 32KB (wq|wk|wv single-buf + ww into buf wbuf) ----
  auto STAGE = [&](int hn, int wbuf){
    #pragma unroll
    for (int i = 0; i < 4; ++i){
      const int obase = w*4096 + i*1024;           // wave-uniform
      const int m   = obase >> 13;                 // 0:wq 1:wk 2:wv 3:ww
      const int row = ((obase & 8191) >> 7) + (l >> 3);
      const int sc  = (l & 7) << 4;
      const char* src;
      int dst;
      if (m == 3){
        src = (const char*)wwbf + row*1024 + hn*128 + (sc ^ ((row & 7) << 4));
        dst = LDS_WW + wbuf*8192 + (obase - 24576);
      } else {
        const u16* basep = (m == 0) ? wqbf : (m == 1) ? wkbf : wvbf;
        src = (const char*)basep + hn*8192 + row*128 + (sc ^ ((row & 7) << 4));
        dst = LDS_WS + obase;
      }
      __builtin_amdgcn_global_load_lds(
          (const __attribute__((address_space(1))) unsigned int*)src,
          (__attribute__((address_space(3))) unsigned int*)(lds + dst),
          16, 0, 0);
    }
  };

  STAGE(hg*4, 0);

  // ---- bias stage: 3x256 floats for this head group ----
  if (tid < 192){
    const int arr = tid >> 6;          // 0:bQ 1:bK 2:bV
    const int idx = (tid & 63) * 4;
    const float* srcb = (arr==0) ? bQ : (arr==1) ? bK : bV;
    *(float4*)(lds + LDS_BIAS + arr*1024 + idx*4) = *(const float4*)(srcb + hg*256 + idx);
  }

  // ---- persistent X fragments (this wave's 16 rows), f32 -> bf16 ----
  const int xrow = rowbase + w*16 + l15;
  v8bf xq[2], xk[2], xv[2];
  #pragma unroll
  for (int ks = 0; ks < 2; ++ks){
    const float* qp = Q + xrow*64 + ks*32 + g*8;
    const float* kp = K + xrow*64 + ks*32 + g*8;
    const float* vp = V + xrow*64 + ks*32 + g*8;
    xq[ks] = pack8(*(const float4*)qp, *(const float4*)(qp+4));
    xk[ks] = pack8(*(const float4*)kp, *(const float4*)(kp+4));
    xv[ks] = pack8(*(const float4*)vp, *(const float4*)(vp+4));
  }

  __syncthreads();                 // B0: drains stage(h0) + bias + X

  v4f acc_out[4];
  #pragma unroll
  for (int mt = 0; mt < 4; ++mt){ v4f z = {0.f,0.f,0.f,0.f}; acc_out[mt] = z; }

  const int q = w*16 + l15;
  const float* bql = (const float*)(lds + LDS_BIAS);
  const float* bkl = bql + 256;
  const float* bvl = bql + 512;

  for (int hi = 0; hi < 4; ++hi){
    const int h  = hg*4 + hi;
    char* wsb = lds + LDS_WS;

    // ======== proj Q,K (A=W from LDS, B=X regs -> D[m=d][n=q]) ========
    v4f aq[4], ak[4];
    #pragma unroll
    for (int mt = 0; mt < 4; ++mt){
      float4 b4 = *(const float4*)(bql + hi*64 + mt*16 + g*4);
      aq[mt][0]=b4.x; aq[mt][1]=b4.y; aq[mt][2]=b4.z; aq[mt][3]=b4.w;
      float4 c4 = *(const float4*)(bkl + hi*64 + mt*16 + g*4);
      ak[mt][0]=c4.x; ak[mt][1]=c4.y; ak[mt][2]=c4.z; ak[mt][3]=c4.w;
    }
    #pragma unroll
    for (int ks = 0; ks < 2; ++ks){
      #pragma unroll
      for (int mt = 0; mt < 4; ++mt){
        v8bf wqf = *(const v8bf*)(wsb + (mt*16 + l15)*128 + ((ks*64 + g*16) ^ swz));
        aq[mt] = mfma16(wqf, xq[ks], aq[mt]);
      }
      #pragma unroll
      for (int mt = 0; mt < 4; ++mt){
        v8bf wkf = *(const v8bf*)(wsb + 8192 + (mt*16 + l15)*128 + ((ks*64 + g*16) ^ swz));
        ak[mt] = mfma16(wkf, xk[ks], ak[mt]);
      }
    }
    // qf fragments via butterfly (registers only)
    uint2 pq[4];
    #pragma unroll
    for (int mt = 0; mt < 4; ++mt) pq[mt] = pack4(aq[mt]);
    v8bf qf0 = bfly(pq[0], pq[1], srcA, srcB, hi_);
    v8bf qf1 = bfly(pq[2], pq[3], srcA, srcB, hi_);
    // rk write (cross-wave)
    #pragma unroll
    for (int mt = 0; mt < 4; ++mt)
      *(uint2*)(lds + LDS_RK + (w*16 + l15)*128 + ((mt*32 + g*8) ^ swz)) = pack4(ak[mt]);

    // ======== proj V (A=X regs, B=W -> D[m=key][n=d]) -> vt[d][key] ========
    {
      v4f av[4];
      #pragma unroll
      for (int nt = 0; nt < 4; ++nt){
        float bs = bvl[hi*64 + nt*16 + l15];
        av[nt][0]=bs; av[nt][1]=bs; av[nt][2]=bs; av[nt][3]=bs;
      }
      #pragma unroll
      for (int ks = 0; ks < 2; ++ks)
        #pragma unroll
        for (int nt = 0; nt < 4; ++nt){
          v8bf wvf = *(const v8bf*)(wsb + 16384 + (nt*16 + l15)*128 + ((ks*64 + g*16) ^ swz));
          av[nt] = mfma16(xv[ks], wvf, av[nt]);
        }
      #pragma unroll
      for (int nt = 0; nt < 4; ++nt)
        *(uint2*)(lds + LDS_VT + (nt*16 + l15)*256 + ((w*32 + g*8) ^ swz)) = pack4(av[nt]);
    }

    __syncthreads();   // B1: rk, vt visible; wq/wk/wv reads done

    // ---- stage next head's weights (ww goes to the other buffer) ----
    if (hi < 3) STAGE(h+1, (hi+1)&1);

    // ---- pool store for previous head (reads pool buffer (hi-1)&1) ----
    if (hi > 0 && tid < 64){
      const float* pr = (const float*)(lds + LDS_POOL + ((hi-1)&1)*2048);
      float s_ = 0.f;
      #pragma unroll
      for (int p = 0; p < 8; ++p) s_ += pr[p*64 + tid];
      pool[(b*8 + h-1)*4096 + nb*64 + tid] = s_ * (1.0f/128.0f);
    }

    // ======== attention span: graded priority (convoy fix) ========
    setprio_graded(w);

    // ======== S^T = K.Q^T + no-max softmax (causal skip: mt<=w) ========
    float sum = 0.f;
    uint2 pp[8];
    #pragma unroll
    for (int mt = 0; mt < 8; ++mt){
      if (mt > w){ uint2 z; z.x = 0u; z.y = 0u; pp[mt] = z; continue; }
      v4f s4 = {0.f,0.f,0.f,0.f};
      s4 = mfma16(*(const v8bf*)(lds + LDS_RK + (mt*16 + l15)*128 + ((0*64 + g*16) ^ swz)), qf0, s4);
      s4 = mfma16(*(const v8bf*)(lds + LDS_RK + (mt*16 + l15)*128 + ((1*64 + g*16) ^ swz)), qf1, s4);
      v4f e4;
      #pragma unroll
      for (int r = 0; r < 4; ++r){
        const int key = mt*16 + g*4 + r;
        float v_ = (key <= q) ? s4[r]*scale : NEGBIG;
        float p = __expf(v_);
        e4[r] = p;
        sum += p;
      }
      pp[mt] = pack4(e4);
    }
    sum += __shfl_xor(sum, 16);
    sum += __shfl_xor(sum, 32);
    const float inv = 1.0f / sum;

    // ======== O = V^T.P (A=vt, B=P-frags -> D[m=d][n=q]) ========
    v4f oa[4];
    #pragma unroll
    for (int mt = 0; mt < 4; ++mt){ v4f z = {0.f,0.f,0.f,0.f}; oa[mt] = z; }
    const int WKn = (w >> 1) + 1;
    #pragma unroll
    for (int ks = 0; ks < 4; ++ks){
      if (ks >= WKn) continue;
      v8bf pf = bfly(pp[2*ks], pp[2*ks+1], srcA, srcB, hi_);
      #pragma unroll
      for (int mt = 0; mt < 4; ++mt){
        v8bf vf = *(const v8bf*)(lds + LDS_VT + (mt*16 + l15)*256 + ((ks*64 + g*16) ^ swz));
        oa[mt] = mfma16(vf, pf, oa[mt]);
      }
    }

    // deferred softmax normalization
    #pragma unroll
    for (int mt = 0; mt < 4; ++mt){
      oa[mt][0]*=inv; oa[mt][1]*=inv; oa[mt][2]*=inv; oa[mt][3]*=inv;
    }

    // ---- pool partial: reduce over q (= over l15 lanes) ----
    {
      float* prd = (float*)(lds + LDS_POOL + (hi&1)*2048);
      #pragma unroll
      for (int mt = 0; mt < 4; ++mt){
        v4f v = oa[mt];
        #pragma unroll
        for (int s_ = 1; s_ < 16; s_ <<= 1){
          v[0] += __shfl_xor(v[0], s_);
          v[1] += __shfl_xor(v[1], s_);
          v[2] += __shfl_xor(v[2], s_);
          v[3] += __shfl_xor(v[3], s_);
        }
        if (l15 == 0)
          *(float4*)(prd + w*64 + mt*16 + g*4) = make_float4(v[0], v[1], v[2], v[3]);
      }
    }

    // ======== out-proj accumulate: acc_out += Ww_h . O^T (W from LDS) ========
    uint2 po[4];
    #pragma unroll
    for (int mt = 0; mt < 4; ++mt) po[mt] = pack4(oa[mt]);
    v8bf of0 = bfly(po[0], po[1], srcA, srcB, hi_);
    v8bf of1 = bfly(po[2], po[3], srcA, srcB, hi_);
    {
      const char* wwb = lds + LDS_WW + (hi&1)*8192;
      #pragma unroll
      for (int ks = 0; ks < 2; ++ks){
        v8bf off = ks ? of1 : of0;
        #pragma unroll
        for (int mt = 0; mt < 4; ++mt){
          v8bf wf = *(const v8bf*)(wwb + (mt*16 + l15)*128 + ((ks*64 + g*16) ^ swz));
          acc_out[mt] = mfma16(wf, off, acc_out[mt]);
        }
      }
    }

    __builtin_amdgcn_s_setprio(0);
    __syncthreads();   // B2: drains stage(h+1); protects rk/vt/WS reuse
  }

  // ---- pool store for last head of this group ----
  if (tid < 64){
    const float* pr = (const float*)(lds + LDS_POOL + (3&1)*2048);
    float s_ = 0.f;
    #pragma unroll
    for (int p = 0; p < 8; ++p) s_ += pr[p*64 + tid];
    pool[(b*8 + hg*4 + 3)*4096 + nb*64 + tid] = s_ * (1.0f/128.0f);
  }

  // ---- store out-proj partial: oVW[hg][row][dout] ----
  #pragma unroll
  for (int mt = 0; mt < 4; ++mt){
    float4 o;
    o.x = acc_out[mt][0]; o.y = acc_out[mt][1];
    o.z = acc_out[mt][2]; o.w = acc_out[mt][3];
    *(float4*)(oVW + hg*2097152 + (rowbase + w*16 + l15)*64 + mt*16 + g*4) = o;
  }
}

// ---------------------------------------------------------------------------
// Kernel 2 (merged global-attn + final), WAVE-PER-HEAD: wave w of block
// (b,nb) computes row nb of head w's pooled global attention straight from
// `pool` (L2-resident), then its out-proj contribution.  2 barriers.
// out = oVW0 + oVW1 + gadd.
// ---------------------------------------------------------------------------
__global__ __launch_bounds__(512) void k_final(
    const float* __restrict__ oVW, const float* __restrict__ Ww, const float* __restrict__ Wb,
    const float* __restrict__ pool, float* __restrict__ out)
{
  __shared__ float prow[8][64];
  __shared__ float grow[8][64];
  __shared__ float gred[8][64];
  __shared__ float gadd[64];

  const int bid = blockIdx.x;     // b*64 + nb
  const int b = bid >> 6, nb = bid & 63;
  const int rowbase = bid * 128;
  const int tid = threadIdx.x;
  const int w = tid >> 6, l = tid & 63;

  const float* pb = pool + (b*8 + w)*4096;   // this wave's head tile [64k][64d]

  // ---- S row: lane l = key k ----
  float dot = 0.f;
  #pragma unroll
  for (int dd = 0; dd < 16; ++dd){
    float4 t  = *(const float4*)(pb + l*64  + dd*4);
    float4 qv = *(const float4*)(pb + nb*64 + dd*4);
    dot += t.x*qv.x + t.y*qv.y + t.z*qv.z + t.w*qv.w;
  }
  float sv = (l <= nb) ? dot*0.125f : NEGBIG;
  float mx = sv;
  #pragma unroll
  for (int s = 1; s < 64; s <<= 1) mx = fmaxf(mx, __shfl_xor(mx, s));
  float p = __expf(sv - mx);
  float sum = p;
  #pragma unroll
  for (int s = 1; s < 64; s <<= 1) sum += __shfl_xor(sum, s);
  prow[w][l] = p / sum;            // wave-private write->read: no barrier

  // ---- grow[d] = sum_k prow[k]*pool[k][d] (lane l = d; coalesced) ----
  {
    float a = 0.f;
    for (int k = 0; k <= nb; ++k)          // prow[k]=0 for k>nb
      a += prow[w][k] * pb[k*64 + l];
    grow[w][l] = a;
  }

  // ---- per-head out-proj contribution: lane l = dout ----
  {
    const float* wr = Ww + l*512 + w*64;
    float c = 0.f;
    #pragma unroll
    for (int dd = 0; dd < 16; ++dd){
      float4 g4 = *(const float4*)(&grow[w][dd*4]);
      float4 w4 = *(const float4*)(wr + dd*4);
      c += g4.x*w4.x + g4.y*w4.y + g4.z*w4.z + g4.w*w4.w;
    }
    gred[w][l] = c;
  }
  __syncthreads();
  if (tid < 64){
    float s = Wb[tid];
    #pragma unroll
    for (int ph = 0; ph < 8; ++ph) s += gred[ph][tid];
    gadd[tid] = s;
  }
  __syncthreads();

  // ---- out = oVW0 + oVW1 + gadd ----
  const int c4 = (tid & 15) * 4;
  float4 ga = *(const float4*)(&gadd[c4]);
  #pragma unroll
  for (int it = 0; it < 4; ++it){
    const int row = it*32 + (tid >> 4);
    const int idx = (rowbase + row)*64 + c4;
    float4 v0 = *(const float4*)(oVW + idx);
    float4 v1 = *(const float4*)(oVW + 2097152 + idx);
    float4 o;
    o.x = v0.x + v1.x + ga.x; o.y = v0.y + v1.y + ga.y;
    o.z = v0.z + v1.z + ga.z; o.w = v0.w + v1.w + ga.w;
    *(float4*)(out + idx) = o;
  }
}

// ---------------------------------------------------------------------------

extern "C" void kernel_launch(void* const* d_in, const int* in_sizes, int n_in,
                              void* d_out, int out_size, void* d_ws, size_t ws_size,
                              hipStream_t stream) {
  const float* Q   = (const float*)d_in[0];
  const float* K   = (const float*)d_in[1];
  const float* V   = (const float*)d_in[2];
  const float* WQw = (const float*)d_in[3];
  const float* WQb = (const float*)d_in[4];
  const float* WKw = (const float*)d_in[5];
  const float* WKb = (const float*)d_in[6];
  const float* WVw = (const float*)d_in[7];
  const float* WVb = (const float*)d_in[8];
  const float* Ww  = (const float*)d_in[9];
  const float* Wb  = (const float*)d_in[10];

  char* ws = (char*)d_ws;
  float* oVW  = (float*)(ws + 0);          // 2 x 8,388,608 B
  float* pool = (float*)(ws + 16777216);   //   524,288 B
  u16*   wqbf = (u16*)(ws + 17825792);     //    65,536 B each
  u16*   wkbf = (u16*)(ws + 17891328);
  u16*   wvbf = (u16*)(ws + 17956864);
  u16*   wwbf = (u16*)(ws + 18022400);

  float* outp = (float*)d_out;

  k_pre<<<128, 256, 0, stream>>>(WQw, WKw, WVw, Ww, wqbf, wkbf, wvbf, wwbf);
  k_fused<<<512, 512, LDS_TOTAL, stream>>>(Q, K, V, wqbf, wkbf, wvbf, wwbf,
                                           WQb, WKb, WVb, oVW, pool);
  k_final<<<256, 512, 0, stream>>>(oVW, Ww, Wb, pool, outp);
}

// Round 11
// 76.913 us; speedup vs baseline: 1.2201x; 1.0357x over previous
//
#include <hip/hip_runtime.h>
#include <stdint.h>

typedef float  v4f  __attribute__((ext_vector_type(4)));
typedef __bf16 v8bf __attribute__((ext_vector_type(8)));
typedef __bf16 v4bf __attribute__((ext_vector_type(4)));
typedef unsigned short u16;

#define NEGBIG (-1.0e9f)

static __device__ __forceinline__ uint2 pack4(v4f a){
  v4bf r;
  r[0]=(__bf16)a[0]; r[1]=(__bf16)a[1]; r[2]=(__bf16)a[2]; r[3]=(__bf16)a[3];
  return __builtin_bit_cast(uint2, r);
}
static __device__ __forceinline__ v8bf pack8(float4 a, float4 b){
  v8bf r;
  r[0]=(__bf16)a.x; r[1]=(__bf16)a.y; r[2]=(__bf16)a.z; r[3]=(__bf16)a.w;
  r[4]=(__bf16)b.x; r[5]=(__bf16)b.y; r[6]=(__bf16)b.z; r[7]=(__bf16)b.w;
  return r;
}
static __device__ __forceinline__ v4f mfma16(v8bf a, v8bf b, v4f c){
  return __builtin_amdgcn_mfma_f32_16x16x32_bf16(a, b, c, 0, 0, 0);
}

// s_setprio takes an IMMEDIATE -> select constant calls wave-uniformly.
static __device__ __forceinline__ void setprio_graded(int w){
  if (w >= 6)      __builtin_amdgcn_s_setprio(3);
  else if (w >= 4) __builtin_amdgcn_s_setprio(2);
  else if (w >= 2) __builtin_amdgcn_s_setprio(1);
  else             __builtin_amdgcn_s_setprio(0);
}

// Butterfly (kept only for the PV P-fragments; qf/of now go via LDS scratch):
static __device__ __forceinline__ v8bf bfly(uint2 t0, uint2 t1, int srcA, int srcB, int hi){
  int a0 = __shfl((int)t0.x, srcA), a1 = __shfl((int)t0.y, srcA);
  int b0 = __shfl((int)t1.x, srcA), b1 = __shfl((int)t1.y, srcA);
  int a2 = __shfl((int)t0.x, srcB), a3 = __shfl((int)t0.y, srcB);
  int b2 = __shfl((int)t1.x, srcB), b3 = __shfl((int)t1.y, srcB);
  uint4 r;
  r.x = hi ? (unsigned)b0 : (unsigned)a0;
  r.y = hi ? (unsigned)b1 : (unsigned)a1;
  r.z = hi ? (unsigned)b2 : (unsigned)a2;
  r.w = hi ? (unsigned)b3 : (unsigned)a3;
  return __builtin_bit_cast(v8bf, r);
}

// ---------------------------------------------------------------------------
// Kernel 0: convert the four weight matrices to bf16 (each 32768 elements).
// ---------------------------------------------------------------------------
__global__ __launch_bounds__(256) void k_pre(
    const float* __restrict__ WQ, const float* __restrict__ WK,
    const float* __restrict__ WV, const float* __restrict__ Ww,
    u16* __restrict__ wq, u16* __restrict__ wk,
    u16* __restrict__ wv, u16* __restrict__ ww)
{
  const int seg = blockIdx.x >> 5;
  const int idx = ((blockIdx.x & 31)*256 + threadIdx.x)*4;
  const float* s = (seg==0) ? WQ : (seg==1) ? WK : (seg==2) ? WV : Ww;
  u16*       dst = (seg==0) ? wq : (seg==1) ? wk : (seg==2) ? wv : ww;
  float4 v = *(const float4*)(s + idx);
  v4f a; a[0]=v.x; a[1]=v.y; a[2]=v.z; a[3]=v.w;
  *(uint2*)(dst + idx) = pack4(a);
}

// ---------------------------------------------------------------------------
// LDS map (bytes).  Total 80896 -> 2 blocks/CU.
//  rk   [128 key][64 d] bf16, 128B rows, XOR swz        [0, 16K)
//  vt   [64 d][128 key] bf16, 256B rows, XOR swz        [16K, 32K)
//  WS   wq|wk|wv head slice (24K, single-buffered)      [32K, 56K)
//  QS   per-wave D-layout->fragment scratch, 8 x 2KB    [56K, 72K)
//         (replaces 16-bpermute bfly for qf and of with
//          4x ds_write_b64 + 2x ds_read_b128; wave-private)
//  POOL 2 x 2KB (8 waves x 64 f32), double-buffered     [72K, 76K)
//  BIAS bQ|bK|bV for the 4 heads of this group, 3KB     [76K, 79K)
// ww (out-proj W) reads from GLOBAL (L2-hot; staging it measured ~neutral,
// round 5) -- its 16KB LDS went to QS instead.
// HARD CONSTRAINT: VGPR <= 64 (round 6: 88 VGPR -> 1 block/CU, -27us).
// Occupancy is pinned at ~16 waves/CU in every config (rounds 3/8) -- all
// occupancy-directed moves are dead.  XCD tile-pairing cut FETCH 32->19MB
// with no time change (round 10): k_fused is execution-side bound.
// ---------------------------------------------------------------------------
#define LDS_RK    0
#define LDS_VT    16384
#define LDS_WS    32768
#define LDS_QS    57344
#define LDS_POOL  73728
#define LDS_BIAS  77824
#define LDS_TOTAL 80896

// ---------------------------------------------------------------------------
// Kernel 1 (mega-fused): block = (b, nb, hg); 4 heads; 8 waves; wave w owns
// q rows [16w,16w+16).  hg = bid>>8 so a tile's two blocks share an XCD.
// ---------------------------------------------------------------------------
__global__ __launch_bounds__(512, 4) void k_fused(
    const float* __restrict__ Q, const float* __restrict__ K, const float* __restrict__ V,
    const u16* __restrict__ wqbf, const u16* __restrict__ wkbf,
    const u16* __restrict__ wvbf, const u16* __restrict__ wwbf,
    const float* __restrict__ bQ, const float* __restrict__ bK, const float* __restrict__ bV,
    float* __restrict__ oVW, float* __restrict__ pool)
{
  extern __shared__ char lds[];

  const int bid = blockIdx.x;
  const int hg  = bid >> 8;            // 0 for bids 0..255, 1 for 256..511
  const int tile = bid & 255;          // b*64 + nb ; same tile -> same XCD
  const int b = tile >> 6, nb = tile & 63;
  const int rowbase = tile * 128;
  const int tid = threadIdx.x;
  const int w = tid >> 6, l = tid & 63;
  const int l15 = l & 15, g = l >> 4;
  const int swz = (l15 & 7) << 4;
  const int srcA = ((l >> 4) & 1) * 32 + l15;
  const int srcB = srcA + 16;
  const int hi_  = l >> 5;             // g>>1
  const float scale = 0.125f;
  char* const qsc = lds + LDS_QS + w*2048 + l15*128;   // wave-private scratch row

  // ---- async weight stage: 24KB (wq|wk|wv slice of head hn) ----
  auto STAGE = [&](int hn){
    #pragma unroll
    for (int i = 0; i < 3; ++i){
      const int obase = w*3072 + i*1024;           // wave-uniform
      const int m   = obase >> 13;                 // 0:wq 1:wk 2:wv
      const int row = ((obase & 8191) >> 7) + (l >> 3);
      const int sc  = (l & 7) << 4;
      const u16* basep = (m == 0) ? wqbf : (m == 1) ? wkbf : wvbf;
      const char* src = (const char*)basep + hn*8192 + row*128 + (sc ^ ((row & 7) << 4));
      __builtin_amdgcn_global_load_lds(
          (const __attribute__((address_space(1))) unsigned int*)src,
          (__attribute__((address_space(3))) unsigned int*)(lds + LDS_WS + obase),
          16, 0, 0);
    }
  };

  STAGE(hg*4);

  // ---- bias stage: 3x256 floats for this head group ----
  if (tid < 192){
    const int arr = tid >> 6;          // 0:bQ 1:bK 2:bV
    const int idx = (tid & 63) * 4;
    const float* srcb = (arr==0) ? bQ : (arr==1) ? bK : bV;
    *(float4*)(lds + LDS_BIAS + arr*1024 + idx*4) = *(const float4*)(srcb + hg*256 + idx);
  }

  // ---- persistent X fragments (this wave's 16 rows), f32 -> bf16 ----
  const int xrow = rowbase + w*16 + l15;
  v8bf xq[2], xk[2], xv[2];
  #pragma unroll
  for (int ks = 0; ks < 2; ++ks){
    const float* qp = Q + xrow*64 + ks*32 + g*8;
    const float* kp = K + xrow*64 + ks*32 + g*8;
    const float* vp = V + xrow*64 + ks*32 + g*8;
    xq[ks] = pack8(*(const float4*)qp, *(const float4*)(qp+4));
    xk[ks] = pack8(*(const float4*)kp, *(const float4*)(kp+4));
    xv[ks] = pack8(*(const float4*)vp, *(const float4*)(vp+4));
  }

  __syncthreads();                 // B0: drains stage(h0) + bias + X

  v4f acc_out[4];
  #pragma unroll
  for (int mt = 0; mt < 4; ++mt){ v4f z = {0.f,0.f,0.f,0.f}; acc_out[mt] = z; }

  const int q = w*16 + l15;
  const float* bql = (const float*)(lds + LDS_BIAS);
  const float* bkl = bql + 256;
  const float* bvl = bql + 512;

  for (int hi = 0; hi < 4; ++hi){
    const int h  = hg*4 + hi;
    const int hb = h*64;
    char* wsb = lds + LDS_WS;

    // ======== proj Q,K (A=W from LDS, B=X regs -> D[m=d][n=q]) ========
    v4f aq[4], ak[4];
    #pragma unroll
    for (int mt = 0; mt < 4; ++mt){
      float4 b4 = *(const float4*)(bql + hi*64 + mt*16 + g*4);
      aq[mt][0]=b4.x; aq[mt][1]=b4.y; aq[mt][2]=b4.z; aq[mt][3]=b4.w;
      float4 c4 = *(const float4*)(bkl + hi*64 + mt*16 + g*4);
      ak[mt][0]=c4.x; ak[mt][1]=c4.y; ak[mt][2]=c4.z; ak[mt][3]=c4.w;
    }
    #pragma unroll
    for (int ks = 0; ks < 2; ++ks){
      #pragma unroll
      for (int mt = 0; mt < 4; ++mt){
        v8bf wqf = *(const v8bf*)(wsb + (mt*16 + l15)*128 + ((ks*64 + g*16) ^ swz));
        aq[mt] = mfma16(wqf, xq[ks], aq[mt]);
      }
      #pragma unroll
      for (int mt = 0; mt < 4; ++mt){
        v8bf wkf = *(const v8bf*)(wsb + 8192 + (mt*16 + l15)*128 + ((ks*64 + g*16) ^ swz));
        ak[mt] = mfma16(wkf, xk[ks], ak[mt]);
      }
    }
    // qf fragments via wave-private LDS scratch (was: 2 bfly = 16 bpermute)
    #pragma unroll
    for (int mt = 0; mt < 4; ++mt)
      *(uint2*)(qsc + ((mt*32 + g*8) ^ swz)) = pack4(aq[mt]);
    v8bf qf0 = *(const v8bf*)(qsc + ((g*16) ^ swz));
    v8bf qf1 = *(const v8bf*)(qsc + ((64 + g*16) ^ swz));
    // rk write (cross-wave)
    #pragma unroll
    for (int mt = 0; mt < 4; ++mt)
      *(uint2*)(lds + LDS_RK + (w*16 + l15)*128 + ((mt*32 + g*8) ^ swz)) = pack4(ak[mt]);

    // ======== proj V (A=X regs, B=W -> D[m=key][n=d]) -> vt[d][key] ========
    {
      v4f av[4];
      #pragma unroll
      for (int nt = 0; nt < 4; ++nt){
        float bs = bvl[hi*64 + nt*16 + l15];
        av[nt][0]=bs; av[nt][1]=bs; av[nt][2]=bs; av[nt][3]=bs;
      }
      #pragma unroll
      for (int ks = 0; ks < 2; ++ks)
        #pragma unroll
        for (int nt = 0; nt < 4; ++nt){
          v8bf wvf = *(const v8bf*)(wsb + 16384 + (nt*16 + l15)*128 + ((ks*64 + g*16) ^ swz));
          av[nt] = mfma16(xv[ks], wvf, av[nt]);
        }
      #pragma unroll
      for (int nt = 0; nt < 4; ++nt)
        *(uint2*)(lds + LDS_VT + (nt*16 + l15)*256 + ((w*32 + g*8) ^ swz)) = pack4(av[nt]);
    }

    __syncthreads();   // B1: rk, vt visible; wq/wk/wv reads done

    // ---- stage next head's weights ----
    if (hi < 3) STAGE(h+1);

    // ---- pool store for previous head (reads pool buffer (hi-1)&1) ----
    if (hi > 0 && tid < 64){
      const float* pr = (const float*)(lds + LDS_POOL + ((hi-1)&1)*2048);
      float s_ = 0.f;
      #pragma unroll
      for (int p = 0; p < 8; ++p) s_ += pr[p*64 + tid];
      pool[(b*8 + h-1)*4096 + nb*64 + tid] = s_ * (1.0f/128.0f);
    }

    // ======== attention span: graded priority ========
    setprio_graded(w);

    // ======== S^T = K.Q^T + no-max softmax (causal skip: mt<=w) ========
    float sum = 0.f;
    uint2 pp[8];
    #pragma unroll
    for (int mt = 0; mt < 8; ++mt){
      if (mt > w){ uint2 z; z.x = 0u; z.y = 0u; pp[mt] = z; continue; }
      v4f s4 = {0.f,0.f,0.f,0.f};
      s4 = mfma16(*(const v8bf*)(lds + LDS_RK + (mt*16 + l15)*128 + ((0*64 + g*16) ^ swz)), qf0, s4);
      s4 = mfma16(*(const v8bf*)(lds + LDS_RK + (mt*16 + l15)*128 + ((1*64 + g*16) ^ swz)), qf1, s4);
      v4f e4;
      #pragma unroll
      for (int r = 0; r < 4; ++r){
        const int key = mt*16 + g*4 + r;
        float v_ = (key <= q) ? s4[r]*scale : NEGBIG;
        float p = __expf(v_);
        e4[r] = p;
        sum += p;
      }
      pp[mt] = pack4(e4);
    }
    sum += __shfl_xor(sum, 16);
    sum += __shfl_xor(sum, 32);
    const float inv = 1.0f / sum;

    // ======== O = V^T.P (A=vt, B=P-frags -> D[m=d][n=q]) ========
    v4f oa[4];
    #pragma unroll
    for (int mt = 0; mt < 4; ++mt){ v4f z = {0.f,0.f,0.f,0.f}; oa[mt] = z; }
    const int WKn = (w >> 1) + 1;
    #pragma unroll
    for (int ks = 0; ks < 4; ++ks){
      if (ks >= WKn) continue;
      v8bf pf = bfly(pp[2*ks], pp[2*ks+1], srcA, srcB, hi_);
      #pragma unroll
      for (int mt = 0; mt < 4; ++mt){
        v8bf vf = *(const v8bf*)(lds + LDS_VT + (mt*16 + l15)*256 + ((ks*64 + g*16) ^ swz));
        oa[mt] = mfma16(vf, pf, oa[mt]);
      }
    }

    // deferred softmax normalization
    #pragma unroll
    for (int mt = 0; mt < 4; ++mt){
      oa[mt][0]*=inv; oa[mt][1]*=inv; oa[mt][2]*=inv; oa[mt][3]*=inv;
    }

    // ---- pool partial: reduce over q (= over l15 lanes) ----
    {
      float* prd = (float*)(lds + LDS_POOL + (hi&1)*2048);
      #pragma unroll
      for (int mt = 0; mt < 4; ++mt){
        v4f v = oa[mt];
        #pragma unroll
        for (int s_ = 1; s_ < 16; s_ <<= 1){
          v[0] += __shfl_xor(v[0], s_);
          v[1] += __shfl_xor(v[1], s_);
          v[2] += __shfl_xor(v[2], s_);
          v[3] += __shfl_xor(v[3], s_);
        }
        if (l15 == 0)
          *(float4*)(prd + w*64 + mt*16 + g*4) = make_float4(v[0], v[1], v[2], v[3]);
      }
    }

    // ======== out-proj accumulate: acc_out += Ww_h . O^T ========
    // of fragments via wave-private LDS scratch (was: 2 bfly = 16 bpermute);
    // scratch reuse after qf is safe (wave-private, program order).
    #pragma unroll
    for (int mt = 0; mt < 4; ++mt)
      *(uint2*)(qsc + ((mt*32 + g*8) ^ swz)) = pack4(oa[mt]);
    v8bf of0 = *(const v8bf*)(qsc + ((g*16) ^ swz));
    v8bf of1 = *(const v8bf*)(qsc + ((64 + g*16) ^ swz));
    #pragma unroll
    for (int ks = 0; ks < 2; ++ks){
      v8bf off = ks ? of1 : of0;
      #pragma unroll
      for (int mt = 0; mt < 4; ++mt){
        v8bf wf = *(const v8bf*)(wwbf + (mt*16 + l15)*512 + hb + ks*32 + g*8);
        acc_out[mt] = mfma16(wf, off, acc_out[mt]);
      }
    }

    __builtin_amdgcn_s_setprio(0);
    __syncthreads();   // B2: drains stage(h+1); protects rk/vt/WS reuse
  }

  // ---- pool store for last head of this group ----
  if (tid < 64){
    const float* pr = (const float*)(lds + LDS_POOL + (3&1)*2048);
    float s_ = 0.f;
    #pragma unroll
    for (int p = 0; p < 8; ++p) s_ += pr[p*64 + tid];
    pool[(b*8 + hg*4 + 3)*4096 + nb*64 + tid] = s_ * (1.0f/128.0f);
  }

  // ---- store out-proj partial: oVW[hg][row][dout] ----
  #pragma unroll
  for (int mt = 0; mt < 4; ++mt){
    float4 o;
    o.x = acc_out[mt][0]; o.y = acc_out[mt][1];
    o.z = acc_out[mt][2]; o.w = acc_out[mt][3];
    *(float4*)(oVW + hg*2097152 + (rowbase + w*16 + l15)*64 + mt*16 + g*4) = o;
  }
}

// ---------------------------------------------------------------------------
// Kernel 2 (merged global-attn + final), WAVE-PER-HEAD: wave w of block
// (b,nb) computes row nb of head w's pooled global attention straight from
// `pool` (L2-resident), then its out-proj contribution.  2 barriers.
// out = oVW0 + oVW1 + gadd.
// ---------------------------------------------------------------------------
__global__ __launch_bounds__(512) void k_final(
    const float* __restrict__ oVW, const float* __restrict__ Ww, const float* __restrict__ Wb,
    const float* __restrict__ pool, float* __restrict__ out)
{
  __shared__ float prow[8][64];
  __shared__ float grow[8][64];
  __shared__ float gred[8][64];
  __shared__ float gadd[64];

  const int bid = blockIdx.x;     // b*64 + nb
  const int b = bid >> 6, nb = bid & 63;
  const int rowbase = bid * 128;
  const int tid = threadIdx.x;
  const int w = tid >> 6, l = tid & 63;

  const float* pb = pool + (b*8 + w)*4096;   // this wave's head tile [64k][64d]

  // ---- S row: lane l = key k ----
  float dot = 0.f;
  #pragma unroll
  for (int dd = 0; dd < 16; ++dd){
    float4 t  = *(const float4*)(pb + l*64  + dd*4);
    float4 qv = *(const float4*)(pb + nb*64 + dd*4);
    dot += t.x*qv.x + t.y*qv.y + t.z*qv.z + t.w*qv.w;
  }
  float sv = (l <= nb) ? dot*0.125f : NEGBIG;
  float mx = sv;
  #pragma unroll
  for (int s = 1; s < 64; s <<= 1) mx = fmaxf(mx, __shfl_xor(mx, s));
  float p = __expf(sv - mx);
  float sum = p;
  #pragma unroll
  for (int s = 1; s < 64; s <<= 1) sum += __shfl_xor(sum, s);
  prow[w][l] = p / sum;            // wave-private write->read: no barrier

  // ---- grow[d] = sum_k prow[k]*pool[k][d] (lane l = d; coalesced) ----
  {
    float a = 0.f;
    for (int k = 0; k <= nb; ++k)          // prow[k]=0 for k>nb
      a += prow[w][k] * pb[k*64 + l];
    grow[w][l] = a;
  }

  // ---- per-head out-proj contribution: lane l = dout ----
  {
    const float* wr = Ww + l*512 + w*64;
    float c = 0.f;
    #pragma unroll
    for (int dd = 0; dd < 16; ++dd){
      float4 g4 = *(const float4*)(&grow[w][dd*4]);
      float4 w4 = *(const float4*)(wr + dd*4);
      c += g4.x*w4.x + g4.y*w4.y + g4.z*w4.z + g4.w*w4.w;
    }
    gred[w][l] = c;
  }
  __syncthreads();
  if (tid < 64){
    float s = Wb[tid];
    #pragma unroll
    for (int ph = 0; ph < 8; ++ph) s += gred[ph][tid];
    gadd[tid] = s;
  }
  __syncthreads();

  // ---- out = oVW0 + oVW1 + gadd ----
  const int c4 = (tid & 15) * 4;
  float4 ga = *(const float4*)(&gadd[c4]);
  #pragma unroll
  for (int it = 0; it < 4; ++it){
    const int row = it*32 + (tid >> 4);
    const int idx = (rowbase + row)*64 + c4;
    float4 v0 = *(const float4*)(oVW + idx);
    float4 v1 = *(const float4*)(oVW + 2097152 + idx);
    float4 o;
    o.x = v0.x + v1.x + ga.x; o.y = v0.y + v1.y + ga.y;
    o.z = v0.z + v1.z + ga.z; o.w = v0.w + v1.w + ga.w;
    *(float4*)(out + idx) = o;
  }
}

// ---------------------------------------------------------------------------

extern "C" void kernel_launch(void* const* d_in, const int* in_sizes, int n_in,
                              void* d_out, int out_size, void* d_ws, size_t ws_size,
                              hipStream_t stream) {
  const float* Q   = (const float*)d_in[0];
  const float* K   = (const float*)d_in[1];
  const float* V   = (const float*)d_in[2];
  const float* WQw = (const float*)d_in[3];
  const float* WQb = (const float*)d_in[4];
  const float* WKw = (const float*)d_in[5];
  const float* WKb = (const float*)d_in[6];
  const float* WVw = (const float*)d_in[7];
  const float* WVb = (const float*)d_in[8];
  const float* Ww  = (const float*)d_in[9];
  const float* Wb  = (const float*)d_in[10];

  char* ws = (char*)d_ws;
  float* oVW  = (float*)(ws + 0);          // 2 x 8,388,608 B
  float* pool = (float*)(ws + 16777216);   //   524,288 B
  u16*   wqbf = (u16*)(ws + 17825792);     //    65,536 B each
  u16*   wkbf = (u16*)(ws + 17891328);
  u16*   wvbf = (u16*)(ws + 17956864);
  u16*   wwbf = (u16*)(ws + 18022400);

  float* outp = (float*)d_out;

  k_pre<<<128, 256, 0, stream>>>(WQw, WKw, WVw, Ww, wqbf, wkbf, wvbf, wwbf);
  k_fused<<<512, 512, LDS_TOTAL, stream>>>(Q, K, V, wqbf, wkbf, wvbf, wwbf,
                                           WQb, WKb, WVb, oVW, pool);
  k_final<<<256, 512, 0, stream>>>(oVW, Ww, Wb, pool, outp);
}

// Round 13
// 76.372 us; speedup vs baseline: 1.2287x; 1.0071x over previous
//
#include <hip/hip_runtime.h>
#include <stdint.h>

typedef float  v4f  __attribute__((ext_vector_type(4)));
typedef __bf16 v8bf __attribute__((ext_vector_type(8)));
typedef __bf16 v4bf __attribute__((ext_vector_type(4)));
typedef unsigned short u16;

#define NEGBIG (-1.0e9f)

static __device__ __forceinline__ uint2 pack4(v4f a){
  v4bf r;
  r[0]=(__bf16)a[0]; r[1]=(__bf16)a[1]; r[2]=(__bf16)a[2]; r[3]=(__bf16)a[3];
  return __builtin_bit_cast(uint2, r);
}
static __device__ __forceinline__ v8bf pack8(float4 a, float4 b){
  v8bf r;
  r[0]=(__bf16)a.x; r[1]=(__bf16)a.y; r[2]=(__bf16)a.z; r[3]=(__bf16)a.w;
  r[4]=(__bf16)b.x; r[5]=(__bf16)b.y; r[6]=(__bf16)b.z; r[7]=(__bf16)b.w;
  return r;
}
static __device__ __forceinline__ v4f mfma16(v8bf a, v8bf b, v4f c){
  return __builtin_amdgcn_mfma_f32_16x16x32_bf16(a, b, c, 0, 0, 0);
}

// s_setprio takes an IMMEDIATE -> select constant calls wave-uniformly.
static __device__ __forceinline__ void setprio_graded(int w){
  if (w >= 6)      __builtin_amdgcn_s_setprio(3);
  else if (w >= 4) __builtin_amdgcn_s_setprio(2);
  else if (w >= 2) __builtin_amdgcn_s_setprio(1);
  else             __builtin_amdgcn_s_setprio(0);
}

// ---------------------------------------------------------------------------
// Kernel 0: convert the four weight matrices to bf16 (each 32768 elements).
// ---------------------------------------------------------------------------
__global__ __launch_bounds__(256) void k_pre(
    const float* __restrict__ WQ, const float* __restrict__ WK,
    const float* __restrict__ WV, const float* __restrict__ Ww,
    u16* __restrict__ wq, u16* __restrict__ wk,
    u16* __restrict__ wv, u16* __restrict__ ww)
{
  const int seg = blockIdx.x >> 5;
  const int idx = ((blockIdx.x & 31)*256 + threadIdx.x)*4;
  const float* s = (seg==0) ? WQ : (seg==1) ? WK : (seg==2) ? WV : Ww;
  u16*       dst = (seg==0) ? wq : (seg==1) ? wk : (seg==2) ? wv : ww;
  float4 v = *(const float4*)(s + idx);
  v4f a; a[0]=v.x; a[1]=v.y; a[2]=v.z; a[3]=v.w;
  *(uint2*)(dst + idx) = pack4(a);
}

// ---------------------------------------------------------------------------
// LDS map (bytes).  Total 80896 -> 2 blocks/CU.
//  rk   [128 key][64 d] bf16, 128B rows, XOR swz        [0, 16K)
//  vt   [64 d][128 key] bf16, 256B rows, XOR swz        [16K, 32K)
//  WS   wq|wk|wv head slice (24K, single-buffered)      [32K, 56K)
//  QS   per-wave D-layout->fragment scratch, 8 x 2KB    [56K, 72K)
//         (replaces ALL bpermute butterflies: qf, of, and PV's pf --
//          4x ds_write_b64 + 2x ds_read_b128 per 2-fragment conversion)
//  POOL 2 x 2KB (8 waves x 64 f32), double-buffered     [72K, 76K)
//  BIAS bQ|bK|bV for the 4 heads of this group, 3KB     [76K, 79K)
// ww (out-proj W) reads GLOBAL (L2-hot; staging measured neutral, round 5).
// HARD CONSTRAINT: VGPR <= 64 (round 6: 88 VGPR -> 1 block/CU, -27us).
// Occupancy pinned ~16 waves/CU in every config (rounds 3/8).
// Round 10: FETCH -40% with zero time change -> execution-latency bound.
// Round 12: cooperative grid.sync fusion FAILED (launch silently rejected at
// this LDS footprint: 2x80896 within 1.25% of the 160KB cap; validator more
// conservative than HW) -> 3-kernel structure is final.
// ---------------------------------------------------------------------------
#define LDS_RK    0
#define LDS_VT    16384
#define LDS_WS    32768
#define LDS_QS    57344
#define LDS_POOL  73728
#define LDS_BIAS  77824
#define LDS_TOTAL 80896

// ---------------------------------------------------------------------------
// Kernel 1 (mega-fused): block = (b, nb, hg); 4 heads; 8 waves; wave w owns
// q rows [16w,16w+16).  hg = bid>>8 so a tile's two blocks share an XCD.
// All D-layout -> A/B-fragment conversions go through wave-private LDS
// scratch (2KB/wave): write packed rows swizzled, read back as b128.
// ---------------------------------------------------------------------------
__global__ __launch_bounds__(512, 4) void k_fused(
    const float* __restrict__ Q, const float* __restrict__ K, const float* __restrict__ V,
    const u16* __restrict__ wqbf, const u16* __restrict__ wkbf,
    const u16* __restrict__ wvbf, const u16* __restrict__ wwbf,
    const float* __restrict__ bQ, const float* __restrict__ bK, const float* __restrict__ bV,
    float* __restrict__ oVW, float* __restrict__ pool)
{
  extern __shared__ char lds[];

  const int bid = blockIdx.x;
  const int hg  = bid >> 8;            // 0 for bids 0..255, 1 for 256..511
  const int tile = bid & 255;          // b*64 + nb ; same tile -> same XCD
  const int b = tile >> 6, nb = tile & 63;
  const int rowbase = tile * 128;
  const int tid = threadIdx.x;
  const int w = tid >> 6, l = tid & 63;
  const int l15 = l & 15, g = l >> 4;
  const int swz = (l15 & 7) << 4;
  const float scale = 0.125f;
  char* const qsc = lds + LDS_QS + w*2048 + l15*128;   // wave-private scratch row

  // ---- async weight stage: 24KB (wq|wk|wv slice of head hn) ----
  auto STAGE = [&](int hn){
    #pragma unroll
    for (int i = 0; i < 3; ++i){
      const int obase = w*3072 + i*1024;           // wave-uniform
      const int m   = obase >> 13;                 // 0:wq 1:wk 2:wv
      const int row = ((obase & 8191) >> 7) + (l >> 3);
      const int sc  = (l & 7) << 4;
      const u16* basep = (m == 0) ? wqbf : (m == 1) ? wkbf : wvbf;
      const char* src = (const char*)basep + hn*8192 + row*128 + (sc ^ ((row & 7) << 4));
      __builtin_amdgcn_global_load_lds(
          (const __attribute__((address_space(1))) unsigned int*)src,
          (__attribute__((address_space(3))) unsigned int*)(lds + LDS_WS + obase),
          16, 0, 0);
    }
  };

  STAGE(hg*4);

  // ---- bias stage: 3x256 floats for this head group ----
  if (tid < 192){
    const int arr = tid >> 6;          // 0:bQ 1:bK 2:bV
    const int idx = (tid & 63) * 4;
    const float* srcb = (arr==0) ? bQ : (arr==1) ? bK : bV;
    *(float4*)(lds + LDS_BIAS + arr*1024 + idx*4) = *(const float4*)(srcb + hg*256 + idx);
  }

  // ---- persistent X fragments (this wave's 16 rows), f32 -> bf16 ----
  const int xrow = rowbase + w*16 + l15;
  v8bf xq[2], xk[2], xv[2];
  #pragma unroll
  for (int ks = 0; ks < 2; ++ks){
    const float* qp = Q + xrow*64 + ks*32 + g*8;
    const float* kp = K + xrow*64 + ks*32 + g*8;
    const float* vp = V + xrow*64 + ks*32 + g*8;
    xq[ks] = pack8(*(const float4*)qp, *(const float4*)(qp+4));
    xk[ks] = pack8(*(const float4*)kp, *(const float4*)(kp+4));
    xv[ks] = pack8(*(const float4*)vp, *(const float4*)(vp+4));
  }

  __syncthreads();                 // B0: drains stage(h0) + bias + X

  v4f acc_out[4];
  #pragma unroll
  for (int mt = 0; mt < 4; ++mt){ v4f z = {0.f,0.f,0.f,0.f}; acc_out[mt] = z; }

  const int q = w*16 + l15;
  const float* bql = (const float*)(lds + LDS_BIAS);
  const float* bkl = bql + 256;
  const float* bvl = bql + 512;

  for (int hi = 0; hi < 4; ++hi){
    const int h  = hg*4 + hi;
    const int hb = h*64;
    char* wsb = lds + LDS_WS;

    // ======== proj Q,K (A=W from LDS, B=X regs -> D[m=d][n=q]) ========
    v4f aq[4], ak[4];
    #pragma unroll
    for (int mt = 0; mt < 4; ++mt){
      float4 b4 = *(const float4*)(bql + hi*64 + mt*16 + g*4);
      aq[mt][0]=b4.x; aq[mt][1]=b4.y; aq[mt][2]=b4.z; aq[mt][3]=b4.w;
      float4 c4 = *(const float4*)(bkl + hi*64 + mt*16 + g*4);
      ak[mt][0]=c4.x; ak[mt][1]=c4.y; ak[mt][2]=c4.z; ak[mt][3]=c4.w;
    }
    #pragma unroll
    for (int ks = 0; ks < 2; ++ks){
      #pragma unroll
      for (int mt = 0; mt < 4; ++mt){
        v8bf wqf = *(const v8bf*)(wsb + (mt*16 + l15)*128 + ((ks*64 + g*16) ^ swz));
        aq[mt] = mfma16(wqf, xq[ks], aq[mt]);
      }
      #pragma unroll
      for (int mt = 0; mt < 4; ++mt){
        v8bf wkf = *(const v8bf*)(wsb + 8192 + (mt*16 + l15)*128 + ((ks*64 + g*16) ^ swz));
        ak[mt] = mfma16(wkf, xk[ks], ak[mt]);
      }
    }
    // qf fragments via wave-private LDS scratch
    #pragma unroll
    for (int mt = 0; mt < 4; ++mt)
      *(uint2*)(qsc + ((mt*32 + g*8) ^ swz)) = pack4(aq[mt]);
    v8bf qf0 = *(const v8bf*)(qsc + ((g*16) ^ swz));
    v8bf qf1 = *(const v8bf*)(qsc + ((64 + g*16) ^ swz));
    // rk write (cross-wave)
    #pragma unroll
    for (int mt = 0; mt < 4; ++mt)
      *(uint2*)(lds + LDS_RK + (w*16 + l15)*128 + ((mt*32 + g*8) ^ swz)) = pack4(ak[mt]);

    // ======== proj V (A=X regs, B=W -> D[m=key][n=d]) -> vt[d][key] ========
    {
      v4f av[4];
      #pragma unroll
      for (int nt = 0; nt < 4; ++nt){
        float bs = bvl[hi*64 + nt*16 + l15];
        av[nt][0]=bs; av[nt][1]=bs; av[nt][2]=bs; av[nt][3]=bs;
      }
      #pragma unroll
      for (int ks = 0; ks < 2; ++ks)
        #pragma unroll
        for (int nt = 0; nt < 4; ++nt){
          v8bf wvf = *(const v8bf*)(wsb + 16384 + (nt*16 + l15)*128 + ((ks*64 + g*16) ^ swz));
          av[nt] = mfma16(xv[ks], wvf, av[nt]);
        }
      #pragma unroll
      for (int nt = 0; nt < 4; ++nt)
        *(uint2*)(lds + LDS_VT + (nt*16 + l15)*256 + ((w*32 + g*8) ^ swz)) = pack4(av[nt]);
    }

    __syncthreads();   // B1: rk, vt visible; wq/wk/wv reads done

    // ---- stage next head's weights ----
    if (hi < 3) STAGE(h+1);

    // ---- pool store for previous head (reads pool buffer (hi-1)&1) ----
    if (hi > 0 && tid < 64){
      const float* pr = (const float*)(lds + LDS_POOL + ((hi-1)&1)*2048);
      float s_ = 0.f;
      #pragma unroll
      for (int p = 0; p < 8; ++p) s_ += pr[p*64 + tid];
      pool[(b*8 + h-1)*4096 + nb*64 + tid] = s_ * (1.0f/128.0f);
    }

    // ======== attention span: graded priority ========
    setprio_graded(w);

    // ======== S^T = K.Q^T + no-max softmax (causal skip: mt<=w) ========
    float sum = 0.f;
    uint2 pp[8];
    #pragma unroll
    for (int mt = 0; mt < 8; ++mt){
      if (mt > w){ uint2 z; z.x = 0u; z.y = 0u; pp[mt] = z; continue; }
      v4f s4 = {0.f,0.f,0.f,0.f};
      s4 = mfma16(*(const v8bf*)(lds + LDS_RK + (mt*16 + l15)*128 + ((0*64 + g*16) ^ swz)), qf0, s4);
      s4 = mfma16(*(const v8bf*)(lds + LDS_RK + (mt*16 + l15)*128 + ((1*64 + g*16) ^ swz)), qf1, s4);
      v4f e4;
      #pragma unroll
      for (int r = 0; r < 4; ++r){
        const int key = mt*16 + g*4 + r;
        float v_ = (key <= q) ? s4[r]*scale : NEGBIG;
        float p = __expf(v_);
        e4[r] = p;
        sum += p;
      }
      pp[mt] = pack4(e4);
    }
    sum += __shfl_xor(sum, 16);
    sum += __shfl_xor(sum, 32);
    const float inv = 1.0f / sum;

    // ======== O = V^T.P (A=vt, B=P-frags via LDS scratch) ========
    // P-fragment conversion layout == qf conversion (tiles 2ks,2ks+1 pair
    // into one v8bf).  Two tile-halves time-share the 2KB scratch; per-lane
    // LDS program order makes the overwrite safe.  Causal skip preserved
    // via wave-uniform WKn branches.
    v4f oa[4];
    #pragma unroll
    for (int mt = 0; mt < 4; ++mt){ v4f z = {0.f,0.f,0.f,0.f}; oa[mt] = z; }
    const int WKn = (w >> 1) + 1;
    {
      // half A: tiles 0..3 -> pf0 (ks=0), pf1 (ks=1)
      #pragma unroll
      for (int mt = 0; mt < 4; ++mt)
        *(uint2*)(qsc + ((mt*32 + g*8) ^ swz)) = pp[mt];
      v8bf pf0 = *(const v8bf*)(qsc + ((g*16) ^ swz));
      v8bf pf1 = *(const v8bf*)(qsc + ((64 + g*16) ^ swz));
      #pragma unroll
      for (int mt = 0; mt < 4; ++mt){
        v8bf vf = *(const v8bf*)(lds + LDS_VT + (mt*16 + l15)*256 + ((g*16) ^ swz));
        oa[mt] = mfma16(vf, pf0, oa[mt]);
      }
      if (WKn > 1){
        #pragma unroll
        for (int mt = 0; mt < 4; ++mt){
          v8bf vf = *(const v8bf*)(lds + LDS_VT + (mt*16 + l15)*256 + ((64 + g*16) ^ swz));
          oa[mt] = mfma16(vf, pf1, oa[mt]);
        }
      }
      if (WKn > 2){
        // half B: tiles 4..7 -> pf2 (ks=2), pf3 (ks=3), same scratch slots
        #pragma unroll
        for (int mt = 0; mt < 4; ++mt)
          *(uint2*)(qsc + ((mt*32 + g*8) ^ swz)) = pp[4 + mt];
        v8bf pf2 = *(const v8bf*)(qsc + ((g*16) ^ swz));
        v8bf pf3 = *(const v8bf*)(qsc + ((64 + g*16) ^ swz));
        #pragma unroll
        for (int mt = 0; mt < 4; ++mt){
          v8bf vf = *(const v8bf*)(lds + LDS_VT + (mt*16 + l15)*256 + ((128 + g*16) ^ swz));
          oa[mt] = mfma16(vf, pf2, oa[mt]);
        }
        if (WKn > 3){
          #pragma unroll
          for (int mt = 0; mt < 4; ++mt){
            v8bf vf = *(const v8bf*)(lds + LDS_VT + (mt*16 + l15)*256 + ((192 + g*16) ^ swz));
            oa[mt] = mfma16(vf, pf3, oa[mt]);
          }
        }
      }
    }

    // deferred softmax normalization
    #pragma unroll
    for (int mt = 0; mt < 4; ++mt){
      oa[mt][0]*=inv; oa[mt][1]*=inv; oa[mt][2]*=inv; oa[mt][3]*=inv;
    }

    // ---- pool partial: reduce over q (= over l15 lanes) ----
    {
      float* prd = (float*)(lds + LDS_POOL + (hi&1)*2048);
      #pragma unroll
      for (int mt = 0; mt < 4; ++mt){
        v4f v = oa[mt];
        #pragma unroll
        for (int s_ = 1; s_ < 16; s_ <<= 1){
          v[0] += __shfl_xor(v[0], s_);
          v[1] += __shfl_xor(v[1], s_);
          v[2] += __shfl_xor(v[2], s_);
          v[3] += __shfl_xor(v[3], s_);
        }
        if (l15 == 0)
          *(float4*)(prd + w*64 + mt*16 + g*4) = make_float4(v[0], v[1], v[2], v[3]);
      }
    }

    // ======== out-proj accumulate: acc_out += Ww_h . O^T (W global) ========
    #pragma unroll
    for (int mt = 0; mt < 4; ++mt)
      *(uint2*)(qsc + ((mt*32 + g*8) ^ swz)) = pack4(oa[mt]);
    v8bf of0 = *(const v8bf*)(qsc + ((g*16) ^ swz));
    v8bf of1 = *(const v8bf*)(qsc + ((64 + g*16) ^ swz));
    #pragma unroll
    for (int ks = 0; ks < 2; ++ks){
      v8bf off = ks ? of1 : of0;
      #pragma unroll
      for (int mt = 0; mt < 4; ++mt){
        v8bf wf = *(const v8bf*)(wwbf + (mt*16 + l15)*512 + hb + ks*32 + g*8);
        acc_out[mt] = mfma16(wf, off, acc_out[mt]);
      }
    }

    __builtin_amdgcn_s_setprio(0);
    __syncthreads();   // B2: drains stage(h+1); protects rk/vt/WS reuse
  }

  // ---- pool store for last head of this group ----
  if (tid < 64){
    const float* pr = (const float*)(lds + LDS_POOL + (3&1)*2048);
    float s_ = 0.f;
    #pragma unroll
    for (int p = 0; p < 8; ++p) s_ += pr[p*64 + tid];
    pool[(b*8 + hg*4 + 3)*4096 + nb*64 + tid] = s_ * (1.0f/128.0f);
  }

  // ---- store out-proj partial: oVW[hg][row][dout] ----
  #pragma unroll
  for (int mt = 0; mt < 4; ++mt){
    float4 o;
    o.x = acc_out[mt][0]; o.y = acc_out[mt][1];
    o.z = acc_out[mt][2]; o.w = acc_out[mt][3];
    *(float4*)(oVW + hg*2097152 + (rowbase + w*16 + l15)*64 + mt*16 + g*4) = o;
  }
}

// ---------------------------------------------------------------------------
// Kernel 2 (merged global-attn + final), WAVE-PER-HEAD: wave w of block
// (b,nb) computes row nb of head w's pooled global attention straight from
// `pool` (L2-resident), then its out-proj contribution.  2 barriers.
// out = oVW0 + oVW1 + gadd.
// ---------------------------------------------------------------------------
__global__ __launch_bounds__(512) void k_final(
    const float* __restrict__ oVW, const float* __restrict__ Ww, const float* __restrict__ Wb,
    const float* __restrict__ pool, float* __restrict__ out)
{
  __shared__ float prow[8][64];
  __shared__ float grow[8][64];
  __shared__ float gred[8][64];
  __shared__ float gadd[64];

  const int bid = blockIdx.x;     // b*64 + nb
  const int b = bid >> 6, nb = bid & 63;
  const int rowbase = bid * 128;
  const int tid = threadIdx.x;
  const int w = tid >> 6, l = tid & 63;

  const float* pb = pool + (b*8 + w)*4096;   // this wave's head tile [64k][64d]

  // ---- S row: lane l = key k ----
  float dot = 0.f;
  #pragma unroll
  for (int dd = 0; dd < 16; ++dd){
    float4 t  = *(const float4*)(pb + l*64  + dd*4);
    float4 qv = *(const float4*)(pb + nb*64 + dd*4);
    dot += t.x*qv.x + t.y*qv.y + t.z*qv.z + t.w*qv.w;
  }
  float sv = (l <= nb) ? dot*0.125f : NEGBIG;
  float mx = sv;
  #pragma unroll
  for (int s = 1; s < 64; s <<= 1) mx = fmaxf(mx, __shfl_xor(mx, s));
  float p = __expf(sv - mx);
  float sum = p;
  #pragma unroll
  for (int s = 1; s < 64; s <<= 1) sum += __shfl_xor(sum, s);
  prow[w][l] = p / sum;            // wave-private write->read: no barrier

  // ---- grow[d] = sum_k prow[k]*pool[k][d] (lane l = d; coalesced) ----
  {
    float a = 0.f;
    for (int k = 0; k <= nb; ++k)          // prow[k]=0 for k>nb
      a += prow[w][k] * pb[k*64 + l];
    grow[w][l] = a;
  }

  // ---- per-head out-proj contribution: lane l = dout ----
  {
    const float* wr = Ww + l*512 + w*64;
    float c = 0.f;
    #pragma unroll
    for (int dd = 0; dd < 16; ++dd){
      float4 g4 = *(const float4*)(&grow[w][dd*4]);
      float4 w4 = *(const float4*)(wr + dd*4);
      c += g4.x*w4.x + g4.y*w4.y + g4.z*w4.z + g4.w*w4.w;
    }
    gred[w][l] = c;
  }
  __syncthreads();
  if (tid < 64){
    float s = Wb[tid];
    #pragma unroll
    for (int ph = 0; ph < 8; ++ph) s += gred[ph][tid];
    gadd[tid] = s;
  }
  __syncthreads();

  // ---- out = oVW0 + oVW1 + gadd ----
  const int c4 = (tid & 15) * 4;
  float4 ga = *(const float4*)(&gadd[c4]);
  #pragma unroll
  for (int it = 0; it < 4; ++it){
    const int row = it*32 + (tid >> 4);
    const int idx = (rowbase + row)*64 + c4;
    float4 v0 = *(const float4*)(oVW + idx);
    float4 v1 = *(const float4*)(oVW + 2097152 + idx);
    float4 o;
    o.x = v0.x + v1.x + ga.x; o.y = v0.y + v1.y + ga.y;
    o.z = v0.z + v1.z + ga.z; o.w = v0.w + v1.w + ga.w;
    *(float4*)(out + idx) = o;
  }
}

// ---------------------------------------------------------------------------

extern "C" void kernel_launch(void* const* d_in, const int* in_sizes, int n_in,
                              void* d_out, int out_size, void* d_ws, size_t ws_size,
                              hipStream_t stream) {
  const float* Q   = (const float*)d_in[0];
  const float* K   = (const float*)d_in[1];
  const float* V   = (const float*)d_in[2];
  const float* WQw = (const float*)d_in[3];
  const float* WQb = (const float*)d_in[4];
  const float* WKw = (const float*)d_in[5];
  const float* WKb = (const float*)d_in[6];
  const float* WVw = (const float*)d_in[7];
  const float* WVb = (const float*)d_in[8];
  const float* Ww  = (const float*)d_in[9];
  const float* Wb  = (const float*)d_in[10];

  char* ws = (char*)d_ws;
  float* oVW  = (float*)(ws + 0);          // 2 x 8,388,608 B
  float* pool = (float*)(ws + 16777216);   //   524,288 B
  u16*   wqbf = (u16*)(ws + 17825792);     //    65,536 B each
  u16*   wkbf = (u16*)(ws + 17891328);
  u16*   wvbf = (u16*)(ws + 17956864);
  u16*   wwbf = (u16*)(ws + 18022400);

  float* outp = (float*)d_out;

  k_pre<<<128, 256, 0, stream>>>(WQw, WKw, WVw, Ww, wqbf, wkbf, wvbf, wwbf);
  k_fused<<<512, 512, LDS_TOTAL, stream>>>(Q, K, V, wqbf, wkbf, wvbf, wwbf,
                                           WQb, WKb, WVb, oVW, pool);
  k_final<<<256, 512, 0, stream>>>(oVW, Ww, Wb, pool, outp);
}